// Round 8
// baseline (274.386 us; speedup 1.0000x reference)
//
#include <hip/hip_runtime.h>
#include <math.h>

#define NN 5000
#define NE 160000
#define NF 16
#define KS 640      // k per split (8 splits: 7x640 + 520)
#define WTS 648     // LDS k-stride (bf16): 324 words, %32=4 -> 2-way alias = free
#define CAP 128     // per-node edge bucket capacity (max in-deg ~65 @ lambda=32)
#define SCB 625     // scatter-role blocks (625*256 = 160000 = NE exact)
#define GMB 632     // gemm-role blocks (79 x-tiles * 8 k-splits)

typedef __attribute__((ext_vector_type(8))) short bf16x8;  // 4 VGPRs
typedef __attribute__((ext_vector_type(4))) float f32x4;   // MFMA acc

// ws layout (bytes):
// [0,       20000)   cur   : per-node cursor -> in-degree after scatter (zeroed)
// [20000,   340000)  h1    : x@W1 (split-k atomics -> zeroed)
// [340000,  2900000) slots : bucketed edge sources, slots[d*CAP+pos]=src
// [2900000, 3220000) a1    : relu(agg1(h1)+b1)

__device__ __forceinline__ short f2bf(float f) {  // RNE f32->bf16
  union { float f; unsigned u; } v; v.f = f;
  unsigned r = v.u + 0x7FFFu + ((v.u >> 16) & 1u);
  return (short)(r >> 16);
}

// Merged kernel: blocks [0,SCB) bucket edges by dst; blocks [SCB, SCB+GMB)
// compute h1 = x @ W1 via mfma_f32_16x16x32_bf16 (fp32 acc), split-k x8.
// Scatter blocks launch first so their atomics overlap the gemm's x-stream.
__global__ __launch_bounds__(256) void k_gemm_scat(const float* __restrict__ x,
                                                   const float* __restrict__ w1,
                                                   float* __restrict__ h1,
                                                   const int* __restrict__ src,
                                                   const int* __restrict__ dst,
                                                   int* __restrict__ cur,
                                                   int* __restrict__ slots) {
  __shared__ short wt[NF * WTS];  // 20736 B (unused by scatter role)
  const int bid = blockIdx.x;
  const int tid = threadIdx.x;

  if (bid < SCB) {                // ---- scatter role ----
    const int e = bid * 256 + tid;
    if (e < NE) {
      const int d = dst[e];
      const int pos = atomicAdd(&cur[d], 1);
      if (pos < CAP) slots[d * CAP + pos] = src[e];
    }
    return;                       // uniform per block; no barrier crossed
  }

  // ---- gemm role ----
  const int gb = bid - SCB;       // 0..631
  const int bx = gb % 79;
  const int by = gb / 79;
  const int lane = tid & 63;
  const int wv = tid >> 6;
  const int kb = by * KS;
  const int klen = (NN - kb < KS) ? (NN - kb) : KS;   // 640 or 520
  const int nsteps = (klen + 31) >> 5;                // 20 or 17

  // Stage W1[kb..kb+KS) -> wt[n][kk] transposed bf16, zero-padded past NN.
  for (int kk = tid; kk < KS; kk += 256) {
    const int kg = kb + kk;
    if (kg < NN) {
      const float4* __restrict__ wr = (const float4*)(w1 + (size_t)kg * NF);
      const float4 a = wr[0], b = wr[1], c = wr[2], d = wr[3];
      wt[0 * WTS + kk] = f2bf(a.x);  wt[1 * WTS + kk] = f2bf(a.y);
      wt[2 * WTS + kk] = f2bf(a.z);  wt[3 * WTS + kk] = f2bf(a.w);
      wt[4 * WTS + kk] = f2bf(b.x);  wt[5 * WTS + kk] = f2bf(b.y);
      wt[6 * WTS + kk] = f2bf(b.z);  wt[7 * WTS + kk] = f2bf(b.w);
      wt[8 * WTS + kk] = f2bf(c.x);  wt[9 * WTS + kk] = f2bf(c.y);
      wt[10 * WTS + kk] = f2bf(c.z); wt[11 * WTS + kk] = f2bf(c.w);
      wt[12 * WTS + kk] = f2bf(d.x); wt[13 * WTS + kk] = f2bf(d.y);
      wt[14 * WTS + kk] = f2bf(d.z); wt[15 * WTS + kk] = f2bf(d.w);
    } else {
#pragma unroll
      for (int n = 0; n < NF; ++n) wt[n * WTS + kk] = 0;
    }
  }
  __syncthreads();

  const int tile = bx * 4 + wv;   // 0..315 (313 real)
  const int m0 = tile * 16;
  int arow = m0 + (lane & 15);
  if (arow > NN - 1) arow = NN - 1;       // clamp addr; write guarded below
  const float* __restrict__ xr = x + (size_t)arow * NN + kb;
  const int quad = lane >> 4;
  const short* __restrict__ bp = &wt[(lane & 15) * WTS + quad * 8];

  f32x4 acc = {0.f, 0.f, 0.f, 0.f};
  for (int s = 0; s < nsteps; ++s) {
    const int k0 = s * 32 + quad * 8;     // offset within split (8-aligned)
    bf16x8 a;
    if (kb + k0 < NN) {                   // whole 8-chunk valid (NN%8==0)
      const float4 xa = *(const float4*)(xr + k0);
      const float4 xb = *(const float4*)(xr + k0 + 4);
      a[0] = f2bf(xa.x); a[1] = f2bf(xa.y); a[2] = f2bf(xa.z); a[3] = f2bf(xa.w);
      a[4] = f2bf(xb.x); a[5] = f2bf(xb.y); a[6] = f2bf(xb.z); a[7] = f2bf(xb.w);
    } else {
#pragma unroll
      for (int j = 0; j < 8; ++j) a[j] = 0;
    }
    const bf16x8 b = *(const bf16x8*)(bp + s * 32);  // ds_read_b128
    acc = __builtin_amdgcn_mfma_f32_16x16x32_bf16(a, b, acc, 0, 0, 0);
  }

  const int col = lane & 15;
#pragma unroll
  for (int r = 0; r < 4; ++r) {
    const int orow = m0 + quad * 4 + r;
    if (orow < NN) atomicAdd(&h1[orow * NF + col], acc[r]);
  }
}

// Layer-1 aggregation (gather, no atomics), fused bias+ReLU:
//   a1[v][j] = relu(inv[v]*sum_s inv[s]*h1[s][j] + inv[v]^2*h1[v][j] + b1[j])
__global__ __launch_bounds__(256) void k_gather1(const int* __restrict__ slots,
                                                 const int* __restrict__ cnt,
                                                 const float* __restrict__ bias,
                                                 const float* __restrict__ hin,
                                                 float* __restrict__ outp) {
  const int tid = threadIdx.x;
  const int lane = tid & 63;
  const int wv = tid >> 6;
  const int v = blockIdx.x * 4 + wv;
  if (v >= NN) return;
  const int j = lane & 15;
  const int eg = lane >> 4;                 // edge subgroup 0..3
  int deg = cnt[v];
  if (deg > CAP) deg = CAP;
  const int* __restrict__ sl = slots + v * CAP;

  float acc = 0.f;
  int base = 0;
  for (; base + 8 <= deg; base += 8) {      // 2 independent chains per iter
    const int s0 = sl[base + eg];
    const int s1 = sl[base + 4 + eg];
    const float iv0 = rsqrtf((float)cnt[s0] + 1.0f);
    const float iv1 = rsqrtf((float)cnt[s1] + 1.0f);
    acc += iv0 * hin[s0 * NF + j];
    acc += iv1 * hin[s1 * NF + j];
  }
  for (; base < deg; base += 4) {
    const int idx = base + eg;
    if (idx < deg) {
      const int s = sl[idx];
      acc += rsqrtf((float)cnt[s] + 1.0f) * hin[s * NF + j];
    }
  }
  acc += __shfl_xor(acc, 16);
  acc += __shfl_xor(acc, 32);

  if (lane < 16) {
    const float ivv = rsqrtf((float)deg + 1.0f);
    float r = ivv * acc + ivv * ivv * hin[v * NF + j];
    outp[v * NF + j] = fmaxf(r + bias[j], 0.f);
  }
}

// Fused layer-2 aggregation + final GEMM + log_softmax. 4 rows per block,
// 1024 threads (16 waves/CU vs previous 8 -> 2x latency hiding).
// Phase 1: gather g2 rows for v0..v0+3 from a1 (16 subgroups/node).
// Phase 2: thread owns ONE row (r=tid&3) x 20 col-chunks -> ~50 VGPR, no spill.
__global__ __launch_bounds__(1024) void k_final2(const int* __restrict__ slots,
                                                 const int* __restrict__ cnt,
                                                 const float* __restrict__ a1,
                                                 const float* __restrict__ w2,
                                                 const float* __restrict__ b2,
                                                 float* __restrict__ out) {
  __shared__ float zs[4 * NN];      // 80000 B
  __shared__ float pp[16][NF];      // per-wave gather partials
  __shared__ float gsh[4 * NF];
  __shared__ float red[16 * 4];
  __shared__ float rowmax[4];
  __shared__ float rowoff[4];
  const int tid = threadIdx.x;
  const int lane = tid & 63;
  const int wv = tid >> 6;          // 0..15
  const int row0 = blockIdx.x * 4;

  // ---- phase 1: g2 for nodes v0..v0+3 (wave wv -> node wv>>2, quarter wv&3)
  {
    const int r = wv >> 2;
    const int v = row0 + r;
    const int j = lane & 15;
    const int sg = ((wv & 3) << 2) | (lane >> 4);   // 0..15, stride 16
    int deg = cnt[v];
    if (deg > CAP) deg = CAP;
    const int* __restrict__ sl = slots + v * CAP;
    float acc = 0.f;
    for (int idx = sg; idx < deg; idx += 16) {
      const int s = sl[idx];
      acc += rsqrtf((float)cnt[s] + 1.0f) * a1[s * NF + j];
    }
    acc += __shfl_xor(acc, 16);
    acc += __shfl_xor(acc, 32);
    if (lane < 16) pp[wv][j] = acc;
  }
  __syncthreads();
  if (tid < 64) {
    const int r = tid >> 4, j = tid & 15;
    const int v = row0 + r;
    int deg = cnt[v];
    if (deg > CAP) deg = CAP;
    const float ivv = rsqrtf((float)deg + 1.0f);
    const float acc = pp[r * 4 + 0][j] + pp[r * 4 + 1][j] +
                      pp[r * 4 + 2][j] + pp[r * 4 + 3][j];
    gsh[r * NF + j] = ivv * acc + ivv * ivv * a1[v * NF + j];
  }
  __syncthreads();

  // ---- phase 2: z = g2 @ W2 + b2, row-per-thread layout ----
  const int r = tid & 3;            // this thread's row
  const int jb = tid >> 2;          // 0..255 column base
  float gr[NF];
#pragma unroll
  for (int k = 0; k < NF; ++k) gr[k] = gsh[r * NF + k];

  float mx = -1e30f;
  for (int c = 0, jc = jb; c < 20; ++c, jc += 256) {
    if (jc < NN) {
      float z = b2[jc];
#pragma unroll
      for (int k = 0; k < NF; ++k) z = fmaf(gr[k], w2[k * NN + jc], z);
      zs[r * NN + jc] = z;
      mx = fmaxf(mx, z);
    }
  }
  // reduce max over lanes sharing r (lane&3==r): xor offsets 32,16,8,4
#pragma unroll
  for (int off = 32; off >= 4; off >>= 1) mx = fmaxf(mx, __shfl_xor(mx, off));
  if (lane < 4) red[wv * 4 + lane] = mx;   // lane L holds row L&3 = L
  __syncthreads();
  if (tid < 4) {
    float m = red[tid];
#pragma unroll
    for (int w = 1; w < 16; ++w) m = fmaxf(m, red[w * 4 + tid]);
    rowmax[tid] = m;
  }
  __syncthreads();

  const float rm = rowmax[r];
  float sm = 0.f;
  for (int c = 0, jc = jb; c < 20; ++c, jc += 256) {
    if (jc < NN) sm += __expf(zs[r * NN + jc] - rm);
  }
#pragma unroll
  for (int off = 32; off >= 4; off >>= 1) sm += __shfl_xor(sm, off);
  if (lane < 4) red[wv * 4 + lane] = sm;
  __syncthreads();
  if (tid < 4) {
    float s = red[tid];
#pragma unroll
    for (int w = 1; w < 16; ++w) s += red[w * 4 + tid];
    rowoff[tid] = rowmax[tid] + logf(s);
  }
  __syncthreads();

  const float off_r = rowoff[r];
  float* __restrict__ orow = out + (size_t)(row0 + r) * NN;
  for (int c = 0, jc = jb; c < 20; ++c, jc += 256) {
    if (jc < NN) orow[jc] = zs[r * NN + jc] - off_r;
  }
}

extern "C" void kernel_launch(void* const* d_in, const int* in_sizes, int n_in,
                              void* d_out, int out_size, void* d_ws, size_t ws_size,
                              hipStream_t stream) {
  const float* x  = (const float*)d_in[0];
  const int*   src = (const int*)d_in[1];
  const int*   dst = (const int*)d_in[2];
  const float* W1 = (const float*)d_in[3];
  const float* b1 = (const float*)d_in[4];
  const float* W2 = (const float*)d_in[5];
  const float* b2 = (const float*)d_in[6];
  float* out = (float*)d_out;

  char* ws = (char*)d_ws;
  int*   cur   = (int*)(ws);                // [0, 20000)
  float* h1    = (float*)(ws + 20000);      // [20000, 340000)
  int*   slots = (int*)(ws + 340000);       // [340000, 2900000)
  float* a1    = (float*)(ws + 2900000);    // [2900000, 3220000)

  // zero cur + h1 (scatter cursors; split-k atomics accumulate into h1)
  hipMemsetAsync(d_ws, 0, 340000, stream);
  k_gemm_scat<<<SCB + GMB, 256, 0, stream>>>(x, W1, h1, src, dst, cur, slots);
  k_gather1<<<NN / 4, 256, 0, stream>>>(slots, cur, b1, h1, a1);
  k_final2<<<NN / 4, 1024, 0, stream>>>(slots, cur, a1, W2, b2, out);
}

// Round 9
// 255.053 us; speedup vs baseline: 1.0758x; 1.0758x over previous
//
#include <hip/hip_runtime.h>
#include <math.h>

#define NN 5000
#define NE 160000
#define NF 16
#define KS 640      // k per split (8 splits: 7x640 + 520)
#define WTS 648     // LDS k-stride (bf16): 324 words, %32=4 -> 2-way alias = free
#define CAP 128     // per-node edge bucket capacity (max in-deg ~65 @ lambda=32)
#define SCB 625     // scatter-role blocks (625*256 = 160000 = NE exact)
#define GMB 632     // gemm-role blocks (79 x-tiles * 8 k-splits)

typedef __attribute__((ext_vector_type(8))) short bf16x8;  // 4 VGPRs
typedef __attribute__((ext_vector_type(4))) float f32x4;   // MFMA acc

// ws layout (bytes):
// [0,       20000)   cur   : per-node cursor -> in-degree after scatter (zeroed)
// [20000,   340000)  h1    : x@W1 (split-k atomics -> zeroed)
// [340000,  2900000) slots : bucketed edge sources, slots[d*CAP+pos]=src
// [2900000, 3220000) a1    : relu(agg1(h1)+b1)

__device__ __forceinline__ short f2bf(float f) {  // RNE f32->bf16
  union { float f; unsigned u; } v; v.f = f;
  unsigned r = v.u + 0x7FFFu + ((v.u >> 16) & 1u);
  return (short)(r >> 16);
}

// Merged kernel: blocks [0,SCB) bucket edges by dst; blocks [SCB, SCB+GMB)
// compute h1 = x @ W1 via mfma_f32_16x16x32_bf16 (fp32 acc), split-k x8.
// Scatter blocks launch first so their atomics overlap the gemm's x-stream.
__global__ __launch_bounds__(256) void k_gemm_scat(const float* __restrict__ x,
                                                   const float* __restrict__ w1,
                                                   float* __restrict__ h1,
                                                   const int* __restrict__ src,
                                                   const int* __restrict__ dst,
                                                   int* __restrict__ cur,
                                                   int* __restrict__ slots) {
  __shared__ short wt[NF * WTS];  // 20736 B (unused by scatter role)
  const int bid = blockIdx.x;
  const int tid = threadIdx.x;

  if (bid < SCB) {                // ---- scatter role ----
    const int e = bid * 256 + tid;
    if (e < NE) {
      const int d = dst[e];
      const int pos = atomicAdd(&cur[d], 1);
      if (pos < CAP) slots[d * CAP + pos] = src[e];
    }
    return;                       // uniform per block; no barrier crossed
  }

  // ---- gemm role ----
  const int gb = bid - SCB;       // 0..631
  const int bx = gb % 79;
  const int by = gb / 79;
  const int lane = tid & 63;
  const int wv = tid >> 6;
  const int kb = by * KS;
  const int klen = (NN - kb < KS) ? (NN - kb) : KS;   // 640 or 520
  const int nsteps = (klen + 31) >> 5;                // 20 or 17

  // Stage W1[kb..kb+KS) -> wt[n][kk] transposed bf16, zero-padded past NN.
  for (int kk = tid; kk < KS; kk += 256) {
    const int kg = kb + kk;
    if (kg < NN) {
      const float4* __restrict__ wr = (const float4*)(w1 + (size_t)kg * NF);
      const float4 a = wr[0], b = wr[1], c = wr[2], d = wr[3];
      wt[0 * WTS + kk] = f2bf(a.x);  wt[1 * WTS + kk] = f2bf(a.y);
      wt[2 * WTS + kk] = f2bf(a.z);  wt[3 * WTS + kk] = f2bf(a.w);
      wt[4 * WTS + kk] = f2bf(b.x);  wt[5 * WTS + kk] = f2bf(b.y);
      wt[6 * WTS + kk] = f2bf(b.z);  wt[7 * WTS + kk] = f2bf(b.w);
      wt[8 * WTS + kk] = f2bf(c.x);  wt[9 * WTS + kk] = f2bf(c.y);
      wt[10 * WTS + kk] = f2bf(c.z); wt[11 * WTS + kk] = f2bf(c.w);
      wt[12 * WTS + kk] = f2bf(d.x); wt[13 * WTS + kk] = f2bf(d.y);
      wt[14 * WTS + kk] = f2bf(d.z); wt[15 * WTS + kk] = f2bf(d.w);
    } else {
#pragma unroll
      for (int n = 0; n < NF; ++n) wt[n * WTS + kk] = 0;
    }
  }
  __syncthreads();

  const int tile = bx * 4 + wv;   // 0..315 (313 real)
  const int m0 = tile * 16;
  int arow = m0 + (lane & 15);
  if (arow > NN - 1) arow = NN - 1;       // clamp addr; write guarded below
  const float* __restrict__ xr = x + (size_t)arow * NN + kb;
  const int quad = lane >> 4;
  const short* __restrict__ bp = &wt[(lane & 15) * WTS + quad * 8];

  f32x4 acc = {0.f, 0.f, 0.f, 0.f};
  for (int s = 0; s < nsteps; ++s) {
    const int k0 = s * 32 + quad * 8;     // offset within split (8-aligned)
    bf16x8 a;
    if (kb + k0 < NN) {                   // whole 8-chunk valid (NN%8==0)
      const float4 xa = *(const float4*)(xr + k0);
      const float4 xb = *(const float4*)(xr + k0 + 4);
      a[0] = f2bf(xa.x); a[1] = f2bf(xa.y); a[2] = f2bf(xa.z); a[3] = f2bf(xa.w);
      a[4] = f2bf(xb.x); a[5] = f2bf(xb.y); a[6] = f2bf(xb.z); a[7] = f2bf(xb.w);
    } else {
#pragma unroll
      for (int j = 0; j < 8; ++j) a[j] = 0;
    }
    const bf16x8 b = *(const bf16x8*)(bp + s * 32);  // ds_read_b128
    acc = __builtin_amdgcn_mfma_f32_16x16x32_bf16(a, b, acc, 0, 0, 0);
  }

  const int col = lane & 15;
#pragma unroll
  for (int r = 0; r < 4; ++r) {
    const int orow = m0 + quad * 4 + r;
    if (orow < NN) atomicAdd(&h1[orow * NF + col], acc[r]);
  }
}

// Layer-1 aggregation (gather, no atomics), fused bias+ReLU:
//   a1[v][j] = relu(inv[v]*sum_s inv[s]*h1[s][j] + inv[v]^2*h1[v][j] + b1[j])
__global__ __launch_bounds__(256) void k_gather1(const int* __restrict__ slots,
                                                 const int* __restrict__ cnt,
                                                 const float* __restrict__ bias,
                                                 const float* __restrict__ hin,
                                                 float* __restrict__ outp) {
  const int tid = threadIdx.x;
  const int lane = tid & 63;
  const int wv = tid >> 6;
  const int v = blockIdx.x * 4 + wv;
  if (v >= NN) return;
  const int j = lane & 15;
  const int eg = lane >> 4;                 // edge subgroup 0..3
  int deg = cnt[v];
  if (deg > CAP) deg = CAP;
  const int* __restrict__ sl = slots + v * CAP;

  float acc = 0.f;
  int base = 0;
  for (; base + 8 <= deg; base += 8) {      // 2 independent chains per iter
    const int s0 = sl[base + eg];
    const int s1 = sl[base + 4 + eg];
    const float iv0 = rsqrtf((float)cnt[s0] + 1.0f);
    const float iv1 = rsqrtf((float)cnt[s1] + 1.0f);
    acc += iv0 * hin[s0 * NF + j];
    acc += iv1 * hin[s1 * NF + j];
  }
  for (; base < deg; base += 4) {
    const int idx = base + eg;
    if (idx < deg) {
      const int s = sl[idx];
      acc += rsqrtf((float)cnt[s] + 1.0f) * hin[s * NF + j];
    }
  }
  acc += __shfl_xor(acc, 16);
  acc += __shfl_xor(acc, 32);

  if (lane < 16) {
    const float ivv = rsqrtf((float)deg + 1.0f);
    float r = ivv * acc + ivv * ivv * hin[v * NF + j];
    outp[v * NF + j] = fmaxf(r + bias[j], 0.f);
  }
}

// Fused layer-2 aggregation + final GEMM + log_softmax. 4 rows per block,
// 1024 threads. Phase 1: gather g2 rows from a1 (16 subgroups/node, 4 waves).
// Phase 2: COL-per-thread (jc = tid, 5 chunks): wave loads w2 at 256B/instr,
// w[16] registers reused across all 4 rows (0.25 loads/FMA-group) -- the
// proven round-6 layout, now with 2x waves and (LDS<=81920) 2 blocks/CU.
__global__ __launch_bounds__(1024) void k_final3(const int* __restrict__ slots,
                                                 const int* __restrict__ cnt,
                                                 const float* __restrict__ a1,
                                                 const float* __restrict__ w2,
                                                 const float* __restrict__ b2,
                                                 float* __restrict__ out) {
  __shared__ float zs[4 * NN];      // 80000 B
  __shared__ float pp[16][NF];      // 1024 B  per-wave gather partials
  __shared__ float gsh[4 * NF];     // 256 B
  __shared__ float red[16 * 4];     // 256 B
  __shared__ float rowmax[4];       // 16 B
  __shared__ float rowoff[4];       // 16 B   total 81568 <= 81920 -> 2 blk/CU
  const int tid = threadIdx.x;
  const int lane = tid & 63;
  const int wv = tid >> 6;          // 0..15
  const int row0 = blockIdx.x * 4;

  // ---- phase 1: g2 for nodes v0..v0+3 (wave wv -> node wv>>2, quarter wv&3)
  {
    const int r = wv >> 2;
    const int v = row0 + r;
    const int j = lane & 15;
    const int sg = ((wv & 3) << 2) | (lane >> 4);   // 0..15, stride 16
    int deg = cnt[v];
    if (deg > CAP) deg = CAP;
    const int* __restrict__ sl = slots + v * CAP;
    float acc = 0.f;
    for (int idx = sg; idx < deg; idx += 16) {
      const int s = sl[idx];
      acc += rsqrtf((float)cnt[s] + 1.0f) * a1[s * NF + j];
    }
    acc += __shfl_xor(acc, 16);
    acc += __shfl_xor(acc, 32);
    if (lane < 16) pp[wv][j] = acc;
  }
  __syncthreads();
  if (tid < 64) {
    const int r = tid >> 4, j = tid & 15;
    const int v = row0 + r;
    int deg = cnt[v];
    if (deg > CAP) deg = CAP;
    const float ivv = rsqrtf((float)deg + 1.0f);
    const float acc = pp[r * 4 + 0][j] + pp[r * 4 + 1][j] +
                      pp[r * 4 + 2][j] + pp[r * 4 + 3][j];
    gsh[r * NF + j] = ivv * acc + ivv * ivv * a1[v * NF + j];
  }
  __syncthreads();

  // ---- phase 2: z = g2 @ W2 + b2, col-per-thread, w[] shared across rows ----
  float g[4][NF];
#pragma unroll
  for (int r = 0; r < 4; ++r)
#pragma unroll
    for (int k = 0; k < NF; ++k) g[r][k] = gsh[r * NF + k];

  float mx[4] = {-1e30f, -1e30f, -1e30f, -1e30f};
  for (int jc = tid; jc < NN; jc += 1024) {
    float w[NF];
#pragma unroll
    for (int k = 0; k < NF; ++k) w[k] = w2[k * NN + jc];
    const float bb = b2[jc];
#pragma unroll
    for (int r = 0; r < 4; ++r) {
      float z = bb;
#pragma unroll
      for (int k = 0; k < NF; ++k) z = fmaf(g[r][k], w[k], z);
      zs[r * NN + jc] = z;
      mx[r] = fmaxf(mx[r], z);
    }
  }
#pragma unroll
  for (int r = 0; r < 4; ++r) {
    float m = mx[r];
    for (int off = 32; off; off >>= 1) m = fmaxf(m, __shfl_xor(m, off));
    if (lane == 0) red[wv * 4 + r] = m;
  }
  __syncthreads();
  if (tid < 4) {
    float m = red[tid];
#pragma unroll
    for (int w = 1; w < 16; ++w) m = fmaxf(m, red[w * 4 + tid]);
    rowmax[tid] = m;
  }
  __syncthreads();
  const float rm0 = rowmax[0], rm1 = rowmax[1], rm2 = rowmax[2], rm3 = rowmax[3];

  float sm[4] = {0.f, 0.f, 0.f, 0.f};
  for (int jc = tid; jc < NN; jc += 1024) {
    sm[0] += __expf(zs[0 * NN + jc] - rm0);
    sm[1] += __expf(zs[1 * NN + jc] - rm1);
    sm[2] += __expf(zs[2 * NN + jc] - rm2);
    sm[3] += __expf(zs[3 * NN + jc] - rm3);
  }
#pragma unroll
  for (int r = 0; r < 4; ++r) {
    float s = sm[r];
    for (int off = 32; off; off >>= 1) s += __shfl_xor(s, off);
    if (lane == 0) red[wv * 4 + r] = s;
  }
  __syncthreads();
  if (tid < 4) {
    float s = red[tid];
#pragma unroll
    for (int w = 1; w < 16; ++w) s += red[w * 4 + tid];
    rowoff[tid] = rowmax[tid] + logf(s);
  }
  __syncthreads();
  const float o0 = rowoff[0], o1 = rowoff[1], o2 = rowoff[2], o3 = rowoff[3];
  for (int jc = tid; jc < NN; jc += 1024) {
    out[(size_t)(row0 + 0) * NN + jc] = zs[0 * NN + jc] - o0;
    out[(size_t)(row0 + 1) * NN + jc] = zs[1 * NN + jc] - o1;
    out[(size_t)(row0 + 2) * NN + jc] = zs[2 * NN + jc] - o2;
    out[(size_t)(row0 + 3) * NN + jc] = zs[3 * NN + jc] - o3;
  }
}

extern "C" void kernel_launch(void* const* d_in, const int* in_sizes, int n_in,
                              void* d_out, int out_size, void* d_ws, size_t ws_size,
                              hipStream_t stream) {
  const float* x  = (const float*)d_in[0];
  const int*   src = (const int*)d_in[1];
  const int*   dst = (const int*)d_in[2];
  const float* W1 = (const float*)d_in[3];
  const float* b1 = (const float*)d_in[4];
  const float* W2 = (const float*)d_in[5];
  const float* b2 = (const float*)d_in[6];
  float* out = (float*)d_out;

  char* ws = (char*)d_ws;
  int*   cur   = (int*)(ws);                // [0, 20000)
  float* h1    = (float*)(ws + 20000);      // [20000, 340000)
  int*   slots = (int*)(ws + 340000);       // [340000, 2900000)
  float* a1    = (float*)(ws + 2900000);    // [2900000, 3220000)

  // zero cur + h1 (scatter cursors; split-k atomics accumulate into h1)
  hipMemsetAsync(d_ws, 0, 340000, stream);
  k_gemm_scat<<<SCB + GMB, 256, 0, stream>>>(x, W1, h1, src, dst, cur, slots);
  k_gather1<<<NN / 4, 256, 0, stream>>>(slots, cur, b1, h1, a1);
  k_final3<<<NN / 4, 1024, 0, stream>>>(slots, cur, a1, W2, b2, out);
}